// Round 3
// baseline (7253.455 us; speedup 1.0000x reference)
//
#include <hip/hip_runtime.h>
#include <math.h>

// ---------------------------------------------------------------------------
// SoftmaxPeepLSTM: batch-decomposed persistent kernel, ONE barrier per step.
// 4 groups x 16 batch rows; 64 blocks/group; 8 waves/block.
// Round 3 changes vs round 2:
//  - phase B (h @ Wo^T) is K-SPLIT: each block multiplies its own 16 h-cols
//    by the matching Wo K-slice (register-resident, 16KB) and atomicAdds the
//    16x512 f32 partial into an IC-resident logits accumulator -> barrier-2
//    and the bf16 E round-trip buffer are eliminated.
//  - logits uses a 3-slot rotation; "zeroing" seeds slot with bo (bias folded
//    in), done inside the pre-barrier drain window (race-free).
//  - rowsum computed LOCALLY per block (waves 6,7 exp + shuffle reduce) ->
//    no cross-block rowsum atomics; cell applies 1/rowsum to the E-partial.
//  - out_h / out_y / hT / cT stores moved into the barrier-wait shadow.
//  - all blocks now do identical work (less straggler spread).
// ---------------------------------------------------------------------------

typedef __bf16 bf16;
typedef bf16  bf16x8 __attribute__((ext_vector_type(8)));
typedef float f32x4  __attribute__((ext_vector_type(4)));
typedef unsigned long long u64;
typedef unsigned int u32;

#define B_    64
#define T_    512
#define DIN_  512
#define H_    1024
#define DOUT_ 512
#define NBLK  256
#define NTHR  512
#define GBLK  64      // blocks per group
#define GROWS 16      // batch rows per group

__device__ __forceinline__ bf16x8 ld8f(const float* __restrict__ p) {
  const float4 a = *(const float4*)p;
  const float4 b = *(const float4*)(p + 4);
  bf16x8 r;
  r[0]=(bf16)a.x; r[1]=(bf16)a.y; r[2]=(bf16)a.z; r[3]=(bf16)a.w;
  r[4]=(bf16)b.x; r[5]=(bf16)b.y; r[6]=(bf16)b.z; r[7]=(bf16)b.w;
  return r;
}

__device__ __forceinline__ float sigm(float x){ return 1.f/(1.f+__expf(-x)); }

// ---- IC-coherent (agent-scope, relaxed) accessors for cross-block traffic --
__device__ __forceinline__ void st_u64(void* p, u64 v) {
  __hip_atomic_store((u64*)p, v, __ATOMIC_RELAXED, __HIP_MEMORY_SCOPE_AGENT);
}
__device__ __forceinline__ u64 ld_u64(const void* p) {
  return __hip_atomic_load((const u64*)p, __ATOMIC_RELAXED, __HIP_MEMORY_SCOPE_AGENT);
}
__device__ __forceinline__ void st_u32(void* p, u32 v) {
  __hip_atomic_store((u32*)p, v, __ATOMIC_RELAXED, __HIP_MEMORY_SCOPE_AGENT);
}
__device__ __forceinline__ u32 ld_u32(const void* p) {
  return __hip_atomic_load((const u32*)p, __ATOMIC_RELAXED, __HIP_MEMORY_SCOPE_AGENT);
}
__device__ __forceinline__ void st_f32(float* p, float v) {
  __hip_atomic_store(p, v, __ATOMIC_RELAXED, __HIP_MEMORY_SCOPE_AGENT);
}
__device__ __forceinline__ void at_addf(float* p, float v) {
  __hip_atomic_fetch_add(p, v, __ATOMIC_RELAXED, __HIP_MEMORY_SCOPE_AGENT);
}
__device__ __forceinline__ bf16x8 ldh16(const bf16* p) {
  union { u64 q[2]; bf16x8 v; } u;
  u.q[0] = ld_u64(p);
  u.q[1] = ld_u64(p + 4);
  return u.v;
}

__global__ __launch_bounds__(NTHR, 2)
void lstm_kernel(const float* __restrict__ x,  const float* __restrict__ hx,
                 const float* __restrict__ cx, const float* __restrict__ yx,
                 const float* __restrict__ Wi, const float* __restrict__ bi,
                 const float* __restrict__ Wh, const float* __restrict__ bh,
                 const float* __restrict__ Wp, const float* __restrict__ bp,
                 const float* __restrict__ Wo, const float* __restrict__ bo,
                 float* __restrict__ out, char* __restrict__ ws) {
  // ---- workspace (first 32768 B zeroed by hipMemsetAsync) ----
  u32*   flags  = (u32*)ws;                         // 256 lines, 128 B apart
  float* logits = (float*)(ws + 32768);             // [4 groups][3 slots][16][512]
  bf16*  hbuf   = (bf16*)(ws + 32768 + 4*3*GROWS*DOUT_*4); // [2][64][1024]

  // ---- output layout (flat concat, f32) ----
  float* out_h  = out;                              // [64][512][1024]
  float* out_y  = out + (size_t)B_*T_*H_;           // [64][512][512]
  float* out_hT = out_y + (size_t)B_*T_*DOUT_;      // [64][1024]
  float* out_cT = out_hT + B_*H_;                   // [64][1024]
  float* out_yT = out_cT + B_*H_;                   // [64][512]

  const int tid  = threadIdx.x;
  const int bid  = blockIdx.x;
  const int g    = bid & 3;          // group
  const int n    = bid >> 2;         // block within group, 0..63
  const int w    = tid >> 6;         // wave 0..7
  const int lane = tid & 63;
  const int quad = lane >> 4;
  const int ln15 = lane & 15;
  const int r0   = g * GROWS;        // first batch row of this group

  u32*   gfl = flags + (size_t)(g * GBLK) * 32;
  float* lgt = logits + (size_t)g * 3 * GROWS * DOUT_;

  __shared__ float lred[8][16][66];  // phase A cross-wave K-reduce
  __shared__ bf16  hstage[16][16];
  __shared__ float lds_rs[2][16];    // per-row E sums from waves 6,7

  bf16* h0 = hbuf;
  bf16* h1 = hbuf + (size_t)B_*H_;

  // ---- phase A weights: wfrag[ks][ns]; wave w owns K in [w*256, w*256+256).
  // K map: [0,512)=x@Wi, [512,1536)=h@Wh, [1536,2048)=E@Wp.
  bf16x8 wfrag[8][4];
  {
    #pragma unroll
    for (int ks = 0; ks < 8; ++ks) {
      #pragma unroll
      for (int ns = 0; ns < 4; ++ns) {
        const int grow = ns*H_ + n*16 + ln15;
        const int kabs = w*256 + ks*32 + quad*8;
        const float* p;
        if      (w < 2) p = Wi + (size_t)grow * DIN_  + kabs;
        else if (w < 6) p = Wh + (size_t)grow * H_    + (kabs - 512);
        else            p = Wp + (size_t)grow * DOUT_ + (kabs - 1536);
        wfrag[ks][ns] = ld8f(p);
      }
    }
  }

  // ---- phase-B partial weights (ALL blocks): Wo[:, n*16 .. n*16+16) K-slice.
  // B-frag for mfma_16x16x32: lane holds B[col=tile*16+ln15][k=quad*8+j];
  // only k<16 is real (quads 0,1) -- upper half zero-padded.
  bf16x8 wofrag2[4];
  {
    bf16x8 z;
    #pragma unroll
    for (int j = 0; j < 8; ++j) z[j] = (bf16)0.f;
    #pragma unroll
    for (int m = 0; m < 4; ++m) {
      if (quad < 2)
        wofrag2[m] = ld8f(Wo + (size_t)(w*64 + m*16 + ln15)*H_ + n*16 + quad*8);
      else
        wofrag2[m] = z;
    }
  }

  // ---- cell state: threads 0..255 own one (row, hcol) each ----
  const int crow = (tid >> 4) & 15;
  const int chl  = tid & 15;
  const int cb   = r0 + crow;
  const int ccol = n*16 + chl;
  float c = 0.f;
  float bias4[4];
  if (tid < 256) {
    c = cx[(size_t)cb * H_ + ccol];
    #pragma unroll
    for (int gg = 0; gg < 4; ++gg) {
      const int grow = gg*H_ + ccol;
      bias4[gg] = bi[grow] + bh[grow] + bp[grow];
    }
  }

  // ---- per-thread logits seed value (bias bo folded into the "zero") ----
  float bo_mine = 0.f;
  if (tid < 128) bo_mine = bo[(n*128 + tid) & (DOUT_ - 1)];

  // ---- prologue: h0 = hx (bf16 pairs); seed logits slot 0 with bo ----
  {
    const int idx = n * NTHR + tid;                 // 0..32767
    if (idx < GROWS*H_/2) {
      const int row = idx >> 9, c2 = (idx & 511) * 2;
      const float* hp = hx + (size_t)(r0 + row)*H_ + c2;
      union { u32 q; bf16 h[2]; } u;
      u.h[0] = (bf16)hp[0]; u.h[1] = (bf16)hp[1];
      st_u32(h0 + (size_t)(r0 + row)*H_ + c2, u.q);
    }
    if (tid < 128) st_f32(lgt + n*128 + tid, bo_mine);
  }

  // full prologue barrier
  u32 ep = 1;
  {
    asm volatile("s_waitcnt vmcnt(0)" ::: "memory");
    __syncthreads();
    if (tid == 0) st_u32(gfl + (size_t)n * 32, ep);
    if (tid < GBLK) {
      const u32* f = gfl + (size_t)tid * 32;
      while (ld_u32(f) < ep) __builtin_amdgcn_s_sleep(1);
    }
    __syncthreads();
  }

  // ---------------- time loop: ONE barrier per step ----------------
  for (int t = 0; t < T_; ++t) {
    bf16*       hbR = (t & 1) ? h1 : h0;
    bf16*       hbW = (t & 1) ? h0 : h1;
    const float* lgtPrev = lgt + (size_t)((t + 2) % 3) * GROWS * DOUT_; // logits(t-1)
    float*       lgtCur  = lgt + (size_t)(t % 3)       * GROWS * DOUT_; // logits(t)
    float*       lgtNext = lgt + (size_t)((t + 1) % 3) * GROWS * DOUT_; // seed for t+1

    // ---- phase A: gates GEMM (M=16 rows, N=64 gate cols, K split by wave) --
    f32x4 acc[4];
    #pragma unroll
    for (int j = 0; j < 4; ++j) acc[j] = f32x4{0.f, 0.f, 0.f, 0.f};

    if (w < 2) {          // x_t @ Wi^T  (f32 source, cast on the fly)
      const float* base = x + ((size_t)(r0 + ln15)*T_ + t)*DIN_ + w*256 + quad*8;
      #pragma unroll
      for (int ks = 0; ks < 8; ++ks) {
        const bf16x8 a = ld8f(base + ks*32);
        #pragma unroll
        for (int ns = 0; ns < 4; ++ns)
          acc[ns] = __builtin_amdgcn_mfma_f32_16x16x32_bf16(a, wfrag[ks][ns], acc[ns], 0,0,0);
      }
    } else if (w < 6) {   // h(t-1) @ Wh^T
      const bf16* base = hbR + (size_t)(r0 + ln15)*H_ + (w-2)*256 + quad*8;
      #pragma unroll
      for (int ks = 0; ks < 8; ++ks) {
        const bf16x8 a = ldh16(base + ks*32);
        #pragma unroll
        for (int ns = 0; ns < 4; ++ns)
          acc[ns] = __builtin_amdgcn_mfma_f32_16x16x32_bf16(a, wfrag[ks][ns], acc[ns], 0,0,0);
      }
    } else {              // E(t-1) @ Wp^T : E = exp(logits(t-1)) built locally
      float rs = 0.f;
      #pragma unroll
      for (int ks = 0; ks < 8; ++ks) {
        const int col = (w-6)*256 + ks*32 + quad*8;
        float pv[8];
        if (t == 0) {     // initial y: use yx directly (already softmaxed)
          const float* yp = yx + (size_t)(r0 + ln15)*DOUT_ + col;
          const float4 a4 = *(const float4*)yp;
          const float4 b4 = *(const float4*)(yp + 4);
          pv[0]=a4.x; pv[1]=a4.y; pv[2]=a4.z; pv[3]=a4.w;
          pv[4]=b4.x; pv[5]=b4.y; pv[6]=b4.z; pv[7]=b4.w;
        } else {
          const float* pp = lgtPrev + ln15*DOUT_ + col;
          #pragma unroll
          for (int u2 = 0; u2 < 4; ++u2) {
            union { u64 q; float f[2]; } ua; ua.q = ld_u64(pp + u2*2);
            pv[u2*2]   = __expf(ua.f[0]);
            pv[u2*2+1] = __expf(ua.f[1]);
          }
        }
        bf16x8 a;
        #pragma unroll
        for (int j = 0; j < 8; ++j) { rs += pv[j]; a[j] = (bf16)pv[j]; }
        #pragma unroll
        for (int ns = 0; ns < 4; ++ns)
          acc[ns] = __builtin_amdgcn_mfma_f32_16x16x32_bf16(a, wfrag[ks][ns], acc[ns], 0,0,0);
      }
      // in-wave row reduce across quads (lanes l, l^16, l^32, l^48 share a row)
      rs += __shfl_xor(rs, 16);
      rs += __shfl_xor(rs, 32);
      if (quad == 0) lds_rs[w-6][ln15] = rs;
    }

    // cross-wave K reduction through LDS (E-partial stays UNSCALED here)
    #pragma unroll
    for (int ns = 0; ns < 4; ++ns)
      #pragma unroll
      for (int r = 0; r < 4; ++r)
        lred[w][quad*4 + r][ns*16 + ln15] = acc[ns][r];
    __syncthreads();   // sync1: lred + lds_rs ready

    // row-softmax denominators available to everyone now
    float rinv_y = 1.f;
    if (w >= 6 && t > 0)
      rinv_y = 1.f / (lds_rs[0][ln15] + lds_rs[1][ln15]);

    // ---- LSTM cell (applies 1/rowsum to the E-partial) ----
    float hn = 0.f;
    if (tid < 256) {
      const float rsum = lds_rs[0][crow] + lds_rs[1][crow];
      const float rinv = (t == 0) ? 1.f : 1.f / rsum;
      float v[4];
      #pragma unroll
      for (int gg = 0; gg < 4; ++gg) {
        const int cl = gg*16 + chl;
        const float s05 = lred[0][crow][cl] + lred[1][crow][cl] + lred[2][crow][cl]
                        + lred[3][crow][cl] + lred[4][crow][cl] + lred[5][crow][cl];
        const float se  = lred[6][crow][cl] + lred[7][crow][cl];
        v[gg] = s05 + se * rinv + bias4[gg];
      }
      const float ig = sigm(v[0]);
      const float fg = sigm(v[1]);
      const float gv = tanhf(v[2]);
      const float og = sigm(v[3]);
      c = fg * c + ig * gv;
      hn = og * tanhf(c);
      hstage[crow][chl] = (bf16)hn;
    }
    __syncthreads();   // sync2: hstage ready

    // ---- phase-B partial: hstage(16x16) @ Wo[:,slice] -> atomic logits(t) --
    {
      bf16x8 a2;
      #pragma unroll
      for (int j = 0; j < 8; ++j) a2[j] = (bf16)0.f;
      if (quad < 2) a2 = *(const bf16x8*)&hstage[ln15][quad*8];
      #pragma unroll
      for (int m = 0; m < 4; ++m) {
        f32x4 d = f32x4{0.f, 0.f, 0.f, 0.f};
        d = __builtin_amdgcn_mfma_f32_16x16x32_bf16(a2, wofrag2[m], d, 0,0,0);
        #pragma unroll
        for (int r = 0; r < 4; ++r)
          at_addf(lgtCur + (quad*4 + r)*DOUT_ + w*64 + m*16 + ln15, d[r]);
      }
    }

    // publish h(t) chunk (IC-coherent)
    if (tid < 64) {
      const int row = tid >> 2, c4 = (tid & 3) * 4;
      union { u64 q; bf16 h[4]; } u;
      #pragma unroll
      for (int j = 0; j < 4; ++j) u.h[j] = hstage[row][c4 + j];
      st_u64(hbW + (size_t)(r0 + row)*H_ + n*16 + c4, u.q);
    }
    // seed logits slot t+1 with bo (safe: its readers finished before barrier t-1)
    if (tid < 128) st_f32(lgtNext + n*128 + tid, bo_mine);

    // ---- drain + arrive ----
    asm volatile("s_waitcnt vmcnt(0)" ::: "memory");
    __syncthreads();
    ++ep;
    if (tid == 0) st_u32(gfl + (size_t)n * 32, ep);

    // ---- shadow work (overlaps other blocks' arrival + our poll) ----
    if (tid < 256) {
      out_h[((size_t)cb * T_ + t) * H_ + ccol] = hn;
      if (t == T_ - 1) {
        out_hT[(size_t)cb * H_ + ccol] = hn;
        out_cT[(size_t)cb * H_ + ccol] = c;
      }
    }
    if (w >= 6 && n < 8 && t > 0) {   // y(t-1) = E(t-1)/rowsum, this block's slice
      const int col = (w-6)*256 + n*32 + quad*8;
      const float* pp = lgtPrev + ln15*DOUT_ + col;
      float* oy = out_y + ((size_t)(r0 + ln15)*T_ + (t - 1))*DOUT_ + col;
      #pragma unroll
      for (int u2 = 0; u2 < 4; ++u2) {
        union { u64 q; float f[2]; } ua; ua.q = ld_u64(pp + u2*2);
        oy[u2*2]   = __expf(ua.f[0]) * rinv_y;
        oy[u2*2+1] = __expf(ua.f[1]) * rinv_y;
      }
    }

    // ---- wait ----
    if (tid < GBLK) {
      const u32* f = gfl + (size_t)tid * 32;
      while (ld_u32(f) < ep) __builtin_amdgcn_s_sleep(1);
    }
    __syncthreads();
  }

  // ---- epilogue: y(T-1) and yT from logits(T-1) (blocks n<8 of each group) --
  if (n < 8) {
    const float* lp = lgt + (size_t)((T_ + 2) % 3) * GROWS * DOUT_;
    if (w >= 6) {
      float rs = 0.f;
      #pragma unroll
      for (int ks = 0; ks < 8; ++ks) {
        const int col = (w-6)*256 + ks*32 + quad*8;
        const float* pp = lp + ln15*DOUT_ + col;
        #pragma unroll
        for (int u2 = 0; u2 < 4; ++u2) {
          union { u64 q; float f[2]; } ua; ua.q = ld_u64(pp + u2*2);
          rs += __expf(ua.f[0]) + __expf(ua.f[1]);
        }
      }
      rs += __shfl_xor(rs, 16);
      rs += __shfl_xor(rs, 32);
      if (quad == 0) lds_rs[w-6][ln15] = rs;
    }
    __syncthreads();
    if (w >= 6) {
      const float rinv = 1.f / (lds_rs[0][ln15] + lds_rs[1][ln15]);
      const int col = (w-6)*256 + n*32 + quad*8;
      const float* pp = lp + ln15*DOUT_ + col;
      float* oy  = out_y  + ((size_t)(r0 + ln15)*T_ + (T_ - 1))*DOUT_ + col;
      float* oyT = out_yT + (size_t)(r0 + ln15)*DOUT_ + col;
      #pragma unroll
      for (int u2 = 0; u2 < 4; ++u2) {
        union { u64 q; float f[2]; } ua; ua.q = ld_u64(pp + u2*2);
        const float y0 = __expf(ua.f[0]) * rinv;
        const float y1 = __expf(ua.f[1]) * rinv;
        oy[u2*2] = y0;  oy[u2*2+1] = y1;
        oyT[u2*2] = y0; oyT[u2*2+1] = y1;
      }
    }
  }
}

extern "C" void kernel_launch(void* const* d_in, const int* in_sizes, int n_in,
                              void* d_out, int out_size, void* d_ws, size_t ws_size,
                              hipStream_t stream) {
  // zero barrier flags (ws is poisoned 0xAA before every launch)
  (void)hipMemsetAsync(d_ws, 0, 32768, stream);
  hipLaunchKernelGGL(lstm_kernel, dim3(NBLK), dim3(NTHR), 0, stream,
                     (const float*)d_in[0],  (const float*)d_in[1],
                     (const float*)d_in[2],  (const float*)d_in[3],
                     (const float*)d_in[4],  (const float*)d_in[5],
                     (const float*)d_in[6],  (const float*)d_in[7],
                     (const float*)d_in[8],  (const float*)d_in[9],
                     (const float*)d_in[10], (const float*)d_in[11],
                     (float*)d_out, (char*)d_ws);
}

// Round 4
// 6383.652 us; speedup vs baseline: 1.1363x; 1.1363x over previous
//
#include <hip/hip_runtime.h>
#include <math.h>

// ---------------------------------------------------------------------------
// SoftmaxPeepLSTM: batch-decomposed persistent kernel, 2 rendezvous per step,
// gather-only cross-block communication (NO atomics -- round 3's atomic
// scatter-reduce cost 4.6GB of HBM-side RMW traffic).
// 4 groups x 16 batch rows; 64 blocks/group; 8 waves/block.
//  - phase A: gates GEMM, K split by wave (x | h | E), M=16, N=64/block.
//  - phase B: logits, symmetric over ALL 64 blocks (8 cols each, K=1024 over
//    8 waves, 4 MFMA/wave); E published as 256B bf16 tile, triple-buffered.
//  - rowsum computed locally by consumer waves 6,7 (shuffle reduce).
//  - x(t+1)@Wi GEMM + y(t-1) HBM stores run in the post-arrive shadow
//    (overlap other blocks' phase B / stragglers).
//  - out_h/hT/cT stores in the arriveB->pollB shadow.
// ---------------------------------------------------------------------------

typedef __bf16 bf16;
typedef bf16  bf16x8 __attribute__((ext_vector_type(8)));
typedef float f32x4  __attribute__((ext_vector_type(4)));
typedef unsigned long long u64;
typedef unsigned int u32;

#define B_    64
#define T_    512
#define DIN_  512
#define H_    1024
#define DOUT_ 512
#define NBLK  256
#define NTHR  512
#define GBLK  64      // blocks per group
#define GROWS 16      // batch rows per group

__device__ __forceinline__ bf16x8 ld8f(const float* __restrict__ p) {
  const float4 a = *(const float4*)p;
  const float4 b = *(const float4*)(p + 4);
  bf16x8 r;
  r[0]=(bf16)a.x; r[1]=(bf16)a.y; r[2]=(bf16)a.z; r[3]=(bf16)a.w;
  r[4]=(bf16)b.x; r[5]=(bf16)b.y; r[6]=(bf16)b.z; r[7]=(bf16)b.w;
  return r;
}

__device__ __forceinline__ float sigm(float x){ return 1.f/(1.f+__expf(-x)); }

// ---- IC-coherent (agent-scope, relaxed) accessors for cross-block traffic --
__device__ __forceinline__ void st_u64(void* p, u64 v) {
  __hip_atomic_store((u64*)p, v, __ATOMIC_RELAXED, __HIP_MEMORY_SCOPE_AGENT);
}
__device__ __forceinline__ u64 ld_u64(const void* p) {
  return __hip_atomic_load((const u64*)p, __ATOMIC_RELAXED, __HIP_MEMORY_SCOPE_AGENT);
}
__device__ __forceinline__ void st_u32(void* p, u32 v) {
  __hip_atomic_store((u32*)p, v, __ATOMIC_RELAXED, __HIP_MEMORY_SCOPE_AGENT);
}
__device__ __forceinline__ u32 ld_u32(const void* p) {
  return __hip_atomic_load((const u32*)p, __ATOMIC_RELAXED, __HIP_MEMORY_SCOPE_AGENT);
}
__device__ __forceinline__ bf16x8 ldh16(const bf16* p) {
  union { u64 q[2]; bf16x8 v; } u;
  u.q[0] = ld_u64(p);
  u.q[1] = ld_u64(p + 4);
  return u.v;
}

__global__ __launch_bounds__(NTHR, 2)
void lstm_kernel(const float* __restrict__ x,  const float* __restrict__ hx,
                 const float* __restrict__ cx, const float* __restrict__ yx,
                 const float* __restrict__ Wi, const float* __restrict__ bi,
                 const float* __restrict__ Wh, const float* __restrict__ bh,
                 const float* __restrict__ Wp, const float* __restrict__ bp,
                 const float* __restrict__ Wo, const float* __restrict__ bo,
                 float* __restrict__ out, char* __restrict__ ws) {
  // ---- workspace (first 65536 B zeroed by hipMemsetAsync) ----
  u32*  flagsA = (u32*)ws;                            // 256 lines, 128B apart
  u32*  flagsB = (u32*)(ws + 32768);                  // 256 lines, 128B apart
  bf16* hbuf   = (bf16*)(ws + 65536);                 // [2][64][1024]
  bf16* ebuf   = (bf16*)(ws + 65536 + (size_t)2*B_*H_*2);  // [3][64][512]

  // ---- output layout (flat concat, f32) ----
  float* out_h  = out;                                // [64][512][1024]
  float* out_y  = out + (size_t)B_*T_*H_;             // [64][512][512]
  float* out_hT = out_y + (size_t)B_*T_*DOUT_;        // [64][1024]
  float* out_cT = out_hT + B_*H_;                     // [64][1024]
  float* out_yT = out_cT + B_*H_;                     // [64][512]

  const int tid  = threadIdx.x;
  const int bid  = blockIdx.x;
  const int g    = bid & 3;          // group
  const int n    = bid >> 2;         // block within group, 0..63
  const int w    = tid >> 6;         // wave 0..7
  const int lane = tid & 63;
  const int quad = lane >> 4;
  const int ln15 = lane & 15;
  const int r0   = g * GROWS;        // first batch row of this group

  u32* gflA = flagsA + (size_t)(g * GBLK) * 32;
  u32* gflB = flagsB + (size_t)(g * GBLK) * 32;

  __shared__ float lred[8][16][66];  // cross-wave K-reduce (A and B phases)
  __shared__ bf16  hstage[16][16];
  __shared__ float lds_rs[2][16];    // per-row E sums from waves 6,7

  bf16* h0 = hbuf;
  bf16* h1 = hbuf + (size_t)B_*H_;

  // ---- phase A weights: wfrag[ks][ns]; wave w owns K in [w*256, w*256+256).
  // K map: [0,512)=x@Wi, [512,1536)=h@Wh, [1536,2048)=E@Wp.
  bf16x8 wfrag[8][4];
  {
    #pragma unroll
    for (int ks = 0; ks < 8; ++ks) {
      #pragma unroll
      for (int ns = 0; ns < 4; ++ns) {
        const int grow = ns*H_ + n*16 + ln15;
        const int kabs = w*256 + ks*32 + quad*8;
        const float* p;
        if      (w < 2) p = Wi + (size_t)grow * DIN_  + kabs;
        else if (w < 6) p = Wh + (size_t)grow * H_    + (kabs - 512);
        else            p = Wp + (size_t)grow * DOUT_ + (kabs - 1536);
        wfrag[ks][ns] = ld8f(p);
      }
    }
  }

  // ---- phase-B weights: block n owns logits cols [n*8, n*8+8), K=1024 split
  // over 8 waves (128 each). B-frag cols 0..7 real (ln15&7 dup for 8..15).
  bf16x8 wofrag[4];
  {
    #pragma unroll
    for (int ks = 0; ks < 4; ++ks)
      wofrag[ks] = ld8f(Wo + (size_t)(n*8 + (ln15 & 7))*H_ + w*128 + ks*32 + quad*8);
  }
  const float bo_reg = bo[n*8 + (tid & 7)];

  // ---- cell state: threads 0..255 own one (row, hcol) each ----
  const int crow = (tid >> 4) & 15;
  const int chl  = tid & 15;
  const int cb   = r0 + crow;
  const int ccol = n*16 + chl;
  float c = 0.f;
  float bias4[4];
  if (tid < 256) {
    c = cx[(size_t)cb * H_ + ccol];
    #pragma unroll
    for (int gg = 0; gg < 4; ++gg) {
      const int grow = gg*H_ + ccol;
      bias4[gg] = bi[grow] + bh[grow] + bp[grow];
    }
  }

  // ---- prologue: h0 = hx (bf16 pairs, IC-coherent) ----
  {
    const int idx = n * NTHR + tid;                 // 0..32767
    if (idx < GROWS*H_/2) {
      const int row = idx >> 9, c2 = (idx & 511) * 2;
      const float* hp = hx + (size_t)(r0 + row)*H_ + c2;
      union { u32 q; bf16 h[2]; } u;
      u.h[0] = (bf16)hp[0]; u.h[1] = (bf16)hp[1];
      st_u32(h0 + (size_t)(r0 + row)*H_ + c2, u.q);
    }
  }

  // ---- prologue x-GEMM(t=0) for waves 0,1 (persists across loop) ----
  f32x4 acc[4];
  if (w < 2) {
    #pragma unroll
    for (int j = 0; j < 4; ++j) acc[j] = f32x4{0.f, 0.f, 0.f, 0.f};
    const float* base = x + (size_t)(r0 + ln15)*T_*DIN_ + w*256 + quad*8;
    #pragma unroll
    for (int ks = 0; ks < 8; ++ks) {
      const bf16x8 a = ld8f(base + ks*32);
      #pragma unroll
      for (int ns = 0; ns < 4; ++ns)
        acc[ns] = __builtin_amdgcn_mfma_f32_16x16x32_bf16(a, wfrag[ks][ns], acc[ns], 0,0,0);
    }
  }

  // ---- arrive A (epoch 1) ----
  asm volatile("s_waitcnt vmcnt(0)" ::: "memory");
  __syncthreads();
  if (tid == 0) st_u32(gflA + (size_t)n * 32, 1u);

  // ---------------- time loop ----------------
  for (int t = 0; t < T_; ++t) {
    const bf16* hbR = (t & 1) ? h1 : h0;
    bf16*       hbW = (t & 1) ? h0 : h1;
    const bf16* EbR = ebuf + (size_t)((t + 2) % 3) * B_ * DOUT_;  // E(t-1)
    bf16*       EbW = ebuf + (size_t)(t % 3)       * B_ * DOUT_;  // E(t)

    // ---- poll A(t+1) ----
    if (tid < GBLK) {
      const u32* f = gflA + (size_t)tid * 32;
      while (ld_u32(f) < (u32)(t + 1)) __builtin_amdgcn_s_sleep(1);
    }
    __syncthreads();

    float rinv_y = 1.f;

    // ---- phase A: waves 2-5 Wh GEMM; waves 6,7 E GEMM (+local rowsum);
    //      waves 0,1 already hold x-GEMM(t) from the shadow ----
    if (w >= 2 && w < 6) {
      #pragma unroll
      for (int j = 0; j < 4; ++j) acc[j] = f32x4{0.f, 0.f, 0.f, 0.f};
      const bf16* base = hbR + (size_t)(r0 + ln15)*H_ + (w-2)*256 + quad*8;
      #pragma unroll
      for (int ks = 0; ks < 8; ++ks) {
        const bf16x8 a = ldh16(base + ks*32);
        #pragma unroll
        for (int ns = 0; ns < 4; ++ns)
          acc[ns] = __builtin_amdgcn_mfma_f32_16x16x32_bf16(a, wfrag[ks][ns], acc[ns], 0,0,0);
      }
    } else if (w >= 6) {
      #pragma unroll
      for (int j = 0; j < 4; ++j) acc[j] = f32x4{0.f, 0.f, 0.f, 0.f};
      float rs = 0.f;
      if (t == 0) {       // initial y: yx (already softmaxed), rowsum forced 1
        const float* yp0 = yx + (size_t)(r0 + ln15)*DOUT_ + (w-6)*256 + quad*8;
        #pragma unroll
        for (int ks = 0; ks < 8; ++ks) {
          const float4 a4 = *(const float4*)(yp0 + ks*32);
          const float4 b4 = *(const float4*)(yp0 + ks*32 + 4);
          bf16x8 a;
          a[0]=(bf16)a4.x; a[1]=(bf16)a4.y; a[2]=(bf16)a4.z; a[3]=(bf16)a4.w;
          a[4]=(bf16)b4.x; a[5]=(bf16)b4.y; a[6]=(bf16)b4.z; a[7]=(bf16)b4.w;
          rs += a4.x+a4.y+a4.z+a4.w+b4.x+b4.y+b4.z+b4.w;
          #pragma unroll
          for (int ns = 0; ns < 4; ++ns)
            acc[ns] = __builtin_amdgcn_mfma_f32_16x16x32_bf16(a, wfrag[ks][ns], acc[ns], 0,0,0);
        }
      } else {
        const bf16* base = EbR + (size_t)(r0 + ln15)*DOUT_ + (w-6)*256 + quad*8;
        #pragma unroll
        for (int ks = 0; ks < 8; ++ks) {
          const bf16x8 a = ldh16(base + ks*32);
          #pragma unroll
          for (int j = 0; j < 8; ++j) rs += (float)a[j];
          #pragma unroll
          for (int ns = 0; ns < 4; ++ns)
            acc[ns] = __builtin_amdgcn_mfma_f32_16x16x32_bf16(a, wfrag[ks][ns], acc[ns], 0,0,0);
        }
      }
      // lanes l, l^16, l^32, l^48 share row ln15
      rs += __shfl_xor(rs, 16);
      rs += __shfl_xor(rs, 32);
      if (quad == 0) lds_rs[w-6][ln15] = rs;
    }

    // cross-wave K reduction through LDS (E-partial stays UNSCALED)
    #pragma unroll
    for (int ns = 0; ns < 4; ++ns)
      #pragma unroll
      for (int r = 0; r < 4; ++r)
        lred[w][quad*4 + r][ns*16 + ln15] = acc[ns][r];
    __syncthreads();   // sync1: lred + lds_rs ready

    if (w >= 6 && t > 0)
      rinv_y = 1.f / (lds_rs[0][ln15] + lds_rs[1][ln15]);

    // ---- LSTM cell ----
    float hn = 0.f;
    if (tid < 256) {
      const float rsum = lds_rs[0][crow] + lds_rs[1][crow];
      const float rinv = (t == 0) ? 1.f : 1.f / rsum;
      float v[4];
      #pragma unroll
      for (int gg = 0; gg < 4; ++gg) {
        const int cl = gg*16 + chl;
        const float s05 = lred[0][crow][cl] + lred[1][crow][cl] + lred[2][crow][cl]
                        + lred[3][crow][cl] + lred[4][crow][cl] + lred[5][crow][cl];
        const float se  = lred[6][crow][cl] + lred[7][crow][cl];
        v[gg] = s05 + se * rinv + bias4[gg];
      }
      const float ig = sigm(v[0]);
      const float fg = sigm(v[1]);
      const float gv = tanhf(v[2]);
      const float og = sigm(v[3]);
      c = fg * c + ig * gv;
      hn = og * tanhf(c);
      hstage[crow][chl] = (bf16)hn;
    }
    __syncthreads();   // sync2: hstage ready

    // publish h(t) chunk (IC-coherent, wave 0)
    if (tid < 64) {
      const int row = tid >> 2, c4 = (tid & 3) * 4;
      union { u64 q; bf16 h[4]; } u;
      #pragma unroll
      for (int j = 0; j < 4; ++j) u.h[j] = hstage[row][c4 + j];
      st_u64(hbW + (size_t)(r0 + row)*H_ + n*16 + c4, u.q);
    }

    // ---- arrive B(t+1) ----
    asm volatile("s_waitcnt vmcnt(0)" ::: "memory");
    __syncthreads();
    if (tid == 0) st_u32(gflB + (size_t)n * 32, (u32)(t + 1));

    // ---- shadow1: HBM h stores (overlap other blocks' arrival) ----
    if (tid < 256) {
      out_h[((size_t)cb * T_ + t) * H_ + ccol] = hn;
      if (t == T_ - 1) {
        out_hT[(size_t)cb * H_ + ccol] = hn;
        out_cT[(size_t)cb * H_ + ccol] = c;
      }
    }

    // ---- poll B(t+1) ----
    if (tid < GBLK) {
      const u32* f = gflB + (size_t)tid * 32;
      while (ld_u32(f) < (u32)(t + 1)) __builtin_amdgcn_s_sleep(1);
    }
    __syncthreads();

    // ---- phase B: logits[16 x 8 cols], K=1024 over 8 waves ----
    {
      f32x4 a2 = f32x4{0.f, 0.f, 0.f, 0.f};
      const bf16* base = hbW + (size_t)(r0 + ln15)*H_ + w*128 + quad*8;
      #pragma unroll
      for (int ks = 0; ks < 4; ++ks) {
        const bf16x8 af = ldh16(base + ks*32);
        a2 = __builtin_amdgcn_mfma_f32_16x16x32_bf16(af, wofrag[ks], a2, 0,0,0);
      }
      #pragma unroll
      for (int r = 0; r < 4; ++r)
        lred[w][quad*4 + r][ln15] = a2[r];
    }
    __syncthreads();
    if (w < 2) {          // 128 finalize threads: 16 rows x 8 cols
      const int row = (tid >> 3) & 15;
      const int col = tid & 7;
      float s = bo_reg;
      #pragma unroll
      for (int ww = 0; ww < 8; ++ww) s += lred[ww][row][col];
      const float ee = __expf(s);     // no max-sub: |logits| < ~3
      const float e2 = __shfl_down(ee, 1);
      if (!(col & 1)) {
        union { u32 q; bf16 h[2]; } u;
        u.h[0] = (bf16)ee; u.h[1] = (bf16)e2;
        st_u32(EbW + (size_t)(r0 + row)*DOUT_ + n*8 + col, u.q);
      }
    }

    // ---- arrive A(t+2) ----
    asm volatile("s_waitcnt vmcnt(0)" ::: "memory");
    __syncthreads();
    if (tid == 0) st_u32(gflA + (size_t)n * 32, (u32)(t + 2));

    // ---- shadow2: y(t-1) stores + x-GEMM(t+1) (overlap stragglers) ----
    if (t > 0 && w >= 6 && n < 8) {
      const int col = (w-6)*256 + n*32 + quad*8;
      const bf16x8 ev = ldh16(EbR + (size_t)(r0 + ln15)*DOUT_ + col);
      float* oy = out_y + ((size_t)(r0 + ln15)*T_ + (t - 1))*DOUT_ + col;
      float4 o1, o2;
      o1.x = (float)ev[0]*rinv_y; o1.y = (float)ev[1]*rinv_y;
      o1.z = (float)ev[2]*rinv_y; o1.w = (float)ev[3]*rinv_y;
      o2.x = (float)ev[4]*rinv_y; o2.y = (float)ev[5]*rinv_y;
      o2.z = (float)ev[6]*rinv_y; o2.w = (float)ev[7]*rinv_y;
      *(float4*)oy = o1; *(float4*)(oy + 4) = o2;
    }
    if (w < 2 && t + 1 < T_) {
      #pragma unroll
      for (int j = 0; j < 4; ++j) acc[j] = f32x4{0.f, 0.f, 0.f, 0.f};
      const float* base = x + ((size_t)(r0 + ln15)*T_ + (t + 1))*DIN_ + w*256 + quad*8;
      #pragma unroll
      for (int ks = 0; ks < 8; ++ks) {
        const bf16x8 a = ld8f(base + ks*32);
        #pragma unroll
        for (int ns = 0; ns < 4; ++ns)
          acc[ns] = __builtin_amdgcn_mfma_f32_16x16x32_bf16(a, wfrag[ks][ns], acc[ns], 0,0,0);
      }
    }
  }

  // ---- epilogue: y(T-1) and yT (blocks n<8 of each group) ----
  if (tid < GBLK) {
    const u32* f = gflA + (size_t)tid * 32;
    while (ld_u32(f) < (u32)(T_ + 1)) __builtin_amdgcn_s_sleep(1);
  }
  __syncthreads();
  if (n < 8) {
    const bf16* eb = ebuf + (size_t)((T_ - 1) % 3) * B_ * DOUT_;
    if (w >= 6) {
      float rs = 0.f;
      #pragma unroll
      for (int ks = 0; ks < 8; ++ks) {
        const int col = (w-6)*256 + ks*32 + quad*8;
        const bf16x8 ev = ldh16(eb + (size_t)(r0 + ln15)*DOUT_ + col);
        #pragma unroll
        for (int j = 0; j < 8; ++j) rs += (float)ev[j];
      }
      rs += __shfl_xor(rs, 16);
      rs += __shfl_xor(rs, 32);
      if (quad == 0) lds_rs[w-6][ln15] = rs;
    }
    __syncthreads();
    if (w >= 6) {
      const float rinv = 1.f / (lds_rs[0][ln15] + lds_rs[1][ln15]);
      const int col = (w-6)*256 + n*32 + quad*8;
      const bf16x8 ev = ldh16(eb + (size_t)(r0 + ln15)*DOUT_ + col);
      float* oy  = out_y  + ((size_t)(r0 + ln15)*T_ + (T_ - 1))*DOUT_ + col;
      float* oyT = out_yT + (size_t)(r0 + ln15)*DOUT_ + col;
      float4 o1, o2;
      o1.x = (float)ev[0]*rinv; o1.y = (float)ev[1]*rinv;
      o1.z = (float)ev[2]*rinv; o1.w = (float)ev[3]*rinv;
      o2.x = (float)ev[4]*rinv; o2.y = (float)ev[5]*rinv;
      o2.z = (float)ev[6]*rinv; o2.w = (float)ev[7]*rinv;
      *(float4*)oy  = o1; *(float4*)(oy  + 4) = o2;
      *(float4*)oyT = o1; *(float4*)(oyT + 4) = o2;
    }
  }
}

extern "C" void kernel_launch(void* const* d_in, const int* in_sizes, int n_in,
                              void* d_out, int out_size, void* d_ws, size_t ws_size,
                              hipStream_t stream) {
  // zero barrier flag arrays (ws is poisoned 0xAA before every launch)
  (void)hipMemsetAsync(d_ws, 0, 65536, stream);
  hipLaunchKernelGGL(lstm_kernel, dim3(NBLK), dim3(NTHR), 0, stream,
                     (const float*)d_in[0],  (const float*)d_in[1],
                     (const float*)d_in[2],  (const float*)d_in[3],
                     (const float*)d_in[4],  (const float*)d_in[5],
                     (const float*)d_in[6],  (const float*)d_in[7],
                     (const float*)d_in[8],  (const float*)d_in[9],
                     (const float*)d_in[10], (const float*)d_in[11],
                     (float*)d_out, (char*)d_ws);
}